// Round 3
// baseline (405.084 us; speedup 1.0000x reference)
//
#include <hip/hip_runtime.h>
#include <hip/hip_bf16.h>

// CILRS head, MI355X round 3.
// - ONE block per 64 perm-rows does: sp-latent MLP (kept in VGPRs) + branch
//   head + speed head. emb read once from HBM (2nd pass L3-hot).
// - Native bf16 casts (compiler emits v_cvt_pk_bf16_f32).
// - k_wprep: LDS-tiled transpose (coalesced both sides), absorbs cnt-zeroing.
// - LDS 53,248 B -> 3 blocks/CU. Dispatches: wprep, hist, scan, scatter, head.
// ws layout (bytes):
//   0        perm   : (B+384) int32
//   263680   cnt    : 20 ints
//   264192   Wsi2T  : [128][256] bf16   ( 65,536)
//   329728   Wso1T  : [256][640] bf16   (327,680)
//   657408   Wso2T  : [256][256] bf16   (131,072)
//   788480   Wb1T   : [6][256][640] bf16 (1,966,080)
//   2754560  Wb2T   : [6][256][256] bf16 (786,432)  end 3,540,992

#define NB 65536
#define NGRID 1030   // NB/64 + 6

typedef __attribute__((ext_vector_type(8))) short short8;
typedef __attribute__((ext_vector_type(4))) float f32x4;
typedef unsigned short bhalf;
typedef unsigned int u32;

__device__ __forceinline__ bhalf f2b(float x) {
    __hip_bfloat16 h = __float2bfloat16(x);
    return *reinterpret_cast<bhalf*>(&h);
}
__device__ __forceinline__ void gll16(const void* g, void* l) {
    __builtin_amdgcn_global_load_lds(
        (const __attribute__((address_space(1))) u32*)g,
        (__attribute__((address_space(3))) u32*)l, 16, 0, 0);
}
// 64B-row tiles (SA/SB): phys = row*64 + (cb ^ (((row>>1)&3)<<4))
__device__ __forceinline__ int sadr(int row, int cb) {
    return row * 64 + (cb ^ (((row >> 1) & 3) << 4));
}
// 512B-row tile (Y): phys = row*512 + (cb ^ ((row&7)<<4))
__device__ __forceinline__ int yadr(int row, int cb) {
    return row * 512 + (cb ^ ((row & 7) << 4));
}

// -------- weight transpose, 64x64 LDS tiles, + cnt zeroing --------
__global__ __launch_bounds__(256) void k_wprep(
    const float* __restrict__ Wsi2, const float* __restrict__ Wso1,
    const float* __restrict__ Wso2, const float* __restrict__ Wb1,
    const float* __restrict__ Wb2,
    bhalf* __restrict__ Wsi2T, bhalf* __restrict__ Wso1T,
    bhalf* __restrict__ Wso2T, bhalf* __restrict__ Wb1T,
    bhalf* __restrict__ Wb2T, int* __restrict__ cnt) {
    __shared__ float T[64][65];
    const int id = blockIdx.x, t = threadIdx.x;
    if (id == 0 && t < 20) cnt[t] = 0;
    const float* src; bhalf* dst; int K, N, tk, tn, b;
    if (id < 8)        { src = Wsi2; dst = Wsi2T; K = 256; N = 128; b = 0; int tl = id;      tk = tl / 2; tn = tl % 2; }
    else if (id < 48)  { src = Wso1; dst = Wso1T; K = 640; N = 256; b = 0; int tl = id - 8;  tk = tl / 4; tn = tl % 4; }
    else if (id < 64)  { src = Wso2; dst = Wso2T; K = 256; N = 256; b = 0; int tl = id - 48; tk = tl / 4; tn = tl % 4; }
    else if (id < 304) { src = Wb1;  dst = Wb1T;  K = 640; N = 256; int li = id - 64;  b = li / 40; int tl = li % 40; tk = tl / 4; tn = tl % 4; }
    else               { src = Wb2;  dst = Wb2T;  K = 256; N = 256; int li = id - 304; b = li / 16; int tl = li % 16; tk = tl / 4; tn = tl % 4; }
    const int k0 = tk * 64, n0 = tn * 64;
    src += (size_t)b * K * N; dst += (size_t)b * N * K;
    const int c = t & 63, r0 = t >> 6;
#pragma unroll
    for (int j = 0; j < 16; ++j) {
        int r = r0 + j * 4;
        T[r][c] = src[(size_t)(k0 + r) * N + n0 + c];
    }
    __syncthreads();
#pragma unroll
    for (int j = 0; j < 16; ++j) {
        int r = r0 + j * 4;
        dst[(size_t)(n0 + r) * K + k0 + c] = f2b(T[c][r]);
    }
}

__global__ void k_hist(const int* __restrict__ cmd, int* __restrict__ cnt) {
    int idx = blockIdx.x * 256 + threadIdx.x;
    int c = cmd[idx] - 1;
    int lane = threadIdx.x & 63;
    for (int g = 0; g < 6; ++g) {
        unsigned long long m = __ballot(c == g);
        if (m && lane == (__ffsll(m) - 1)) atomicAdd(&cnt[g], __popcll(m));
    }
}

__global__ void k_scan(int* cnt) {
    int off = 0;
    for (int g = 0; g < 6; ++g) {
        cnt[6 + g] = off;
        off += ((cnt[g] + 63) / 64) * 64;
        cnt[13 + g] = 0;
    }
    cnt[12] = off;
}

__global__ void k_scatter(const int* __restrict__ cmd, int* __restrict__ cnt,
                          int* __restrict__ perm) {
    int idx = blockIdx.x * 256 + threadIdx.x;
    int c = cmd[idx] - 1;
    int lane = threadIdx.x & 63;
    int* ctr2 = cnt + 13;
    const int* padoff = cnt + 6;
    for (int g = 0; g < 6; ++g) {
        unsigned long long m = __ballot(c == g);
        if (!m) continue;
        int leader = __ffsll(m) - 1;
        int base = 0;
        if (lane == leader) base = atomicAdd(&ctr2[g], __popcll(m));
        base = __shfl(base, leader);
        if (c == g) {
            int pos = base + __popcll(m & ((1ull << lane) - 1ull));
            perm[padoff[g] + pos] = idx;
        }
    }
}

template <int NG>
__device__ __forceinline__ void stageB(const bhalf* W, int rowStrideB, int kByteOff,
                                       char* SB, int t) {
#pragma unroll
    for (int j = 0; j < NG; ++j) {
        int p = t * 16 + j * 4096;
        int row = p >> 6;
        int lcol = (p & 63) ^ (((row >> 1) & 3) << 4);
        gll16((const char*)W + (size_t)row * rowStrideB + kByteOff + lcol, SB + p);
    }
}

// -------- merged head: sp-latent + branch head + speed head per block --------
__global__ __launch_bounds__(256, 3) void k_head(
    const float* __restrict__ emb, const float* __restrict__ speed,
    const float* __restrict__ Wsi1, const float* __restrict__ bsi1,
    const bhalf* __restrict__ Wsi2T, const float* __restrict__ bsi2,
    const bhalf* __restrict__ Wso1T, const float* __restrict__ bso1,
    const bhalf* __restrict__ Wso2T, const float* __restrict__ bso2,
    const float* __restrict__ Wso3, const float* __restrict__ bso3,
    const bhalf* __restrict__ Wb1T, const float* __restrict__ bb1,
    const bhalf* __restrict__ Wb2T, const float* __restrict__ bb2,
    const float* __restrict__ Wb3, const float* __restrict__ bb3,
    const int* __restrict__ cntbuf, const int* __restrict__ perm,
    float* __restrict__ out) {
    __shared__ __align__(16) char SA[4096];    // [64 rows][32 k] swz
    __shared__ __align__(16) char SB[16384];   // [256 n][32 k] swz
    __shared__ __align__(16) char Yb[32768];   // [64 rows][256] swz
    const int t = threadIdx.x, lane = t & 63, wid = t >> 6;
    const int* padoff = cntbuf + 6;
    const int tstart = blockIdx.x * 64;
    if (tstart >= padoff[6]) return;
    int g = 0;
    while (padoff[g + 1] <= tstart) ++g;
    const int gbase = padoff[g], gcnt = cntbuf[g];
    const int iA = t >> 2;
    const int pA = tstart + iA;
    const int rA = ((pA - gbase) < gcnt) ? perm[pA] : 0;

    const int arow = lane & 15, koff = (lane >> 4) * 16;
    const int sAoff = sadr(iA, (t & 3) * 16);

    // ---------- phase 0: sp = relu(s*Wsi1+bsi1) @ Wsi2 + bsi2 (in VGPRs) ----
    const float s = speed[rA];
    f32x4 asp[4][2];
#pragma unroll
    for (int m = 0; m < 4; ++m)
#pragma unroll
        for (int n = 0; n < 2; ++n)
#pragma unroll
            for (int r = 0; r < 4; ++r) asp[m][n][r] = 0.f;
    for (int kc = 0; kc < 8; ++kc) {
        __syncthreads();
        int kg = kc * 32 + (t & 3) * 8;
        short8 w;
#pragma unroll
        for (int j = 0; j < 8; ++j)
            w[j] = (short)f2b(fmaxf(fmaf(s, Wsi1[kg + j], bsi1[kg + j]), 0.f));
        *(short8*)(SA + sAoff) = w;
        stageB<2>(Wsi2T, 512, kc * 64, SB, t);
        __syncthreads();
        short8 a[4], b[2];
#pragma unroll
        for (int m = 0; m < 4; ++m)
            a[m] = *(const short8*)(SA + sadr(m * 16 + arow, koff));
#pragma unroll
        for (int n = 0; n < 2; ++n)
            b[n] = *(const short8*)(SB + sadr(wid * 32 + n * 16 + arow, koff));
#pragma unroll
        for (int m = 0; m < 4; ++m)
#pragma unroll
            for (int n = 0; n < 2; ++n)
                asp[m][n] = __builtin_amdgcn_mfma_f32_16x16x32_bf16(a[m], b[n], asp[m][n], 0, 0, 0);
    }
    // + bsi2 (no relu)
#pragma unroll
    for (int n = 0; n < 2; ++n) {
        float bias = bsi2[wid * 32 + n * 16 + arow];
#pragma unroll
        for (int m = 0; m < 4; ++m)
#pragma unroll
            for (int r = 0; r < 4; ++r) asp[m][n][r] += bias;
    }

    // ---------- two heads: 0 = branch (g-weights, DOUT=3, sigmoid), 1 = speed
    const bhalf* W1b = Wb1T + (size_t)g * 256 * 640;
    const bhalf* W2b = Wb2T + (size_t)g * 256 * 256;
    for (int head = 0; head < 2; ++head) {
        const bhalf* W1T = head ? Wso1T : W1b;
        const float* b1  = head ? bso1  : bb1 + g * 256;
        const bhalf* W2T = head ? Wso2T : W2b;
        const float* b2  = head ? bso2  : bb2 + g * 256;
        const float* W3  = head ? Wso3  : Wb3 + (size_t)g * 256 * 3;
        const float* b3  = head ? bso3  : bb3 + g * 3;
        const int DOUT = head ? 1 : 3;

        f32x4 acc[4][4];
#pragma unroll
        for (int m = 0; m < 4; ++m)
#pragma unroll
            for (int n = 0; n < 4; ++n)
#pragma unroll
                for (int r = 0; r < 4; ++r) acc[m][n][r] = 0.f;

        // ---- layer 1: K=640 (emb 512 + sp 128), 20 chunks ----
        for (int kc = 0; kc < 20; ++kc) {
            __syncthreads();
            if (kc < 16) {
                int kg = kc * 32 + (t & 3) * 8;
                const float4 f0 = *(const float4*)(emb + (size_t)rA * 512 + kg);
                const float4 f1 = *(const float4*)(emb + (size_t)rA * 512 + kg + 4);
                short8 w;
                w[0] = (short)f2b(f0.x); w[1] = (short)f2b(f0.y);
                w[2] = (short)f2b(f0.z); w[3] = (short)f2b(f0.w);
                w[4] = (short)f2b(f1.x); w[5] = (short)f2b(f1.y);
                w[6] = (short)f2b(f1.z); w[7] = (short)f2b(f1.w);
                *(short8*)(SA + sAoff) = w;
            } else if (wid == kc - 16) {
                // owning wave spills its sp fragment chunk into SA
#pragma unroll
                for (int m = 0; m < 4; ++m)
#pragma unroll
                    for (int n = 0; n < 2; ++n)
#pragma unroll
                        for (int r = 0; r < 4; ++r) {
                            int row = m * 16 + (lane >> 4) * 4 + r;
                            int kl = n * 16 + arow;
                            *(bhalf*)(SA + row * 64 + ((2 * kl) ^ (((row >> 1) & 3) << 4))) =
                                f2b(asp[m][n][r]);
                        }
            }
            stageB<4>(W1T, 1280, kc * 64, SB, t);
            __syncthreads();
            short8 a[4], b[4];
#pragma unroll
            for (int m = 0; m < 4; ++m)
                a[m] = *(const short8*)(SA + sadr(m * 16 + arow, koff));
#pragma unroll
            for (int n = 0; n < 4; ++n)
                b[n] = *(const short8*)(SB + sadr(wid * 64 + n * 16 + arow, koff));
#pragma unroll
            for (int m = 0; m < 4; ++m)
#pragma unroll
                for (int n = 0; n < 4; ++n)
                    acc[m][n] = __builtin_amdgcn_mfma_f32_16x16x32_bf16(a[m], b[n], acc[m][n], 0, 0, 0);
        }
        // epi 1: bias+relu -> Y
#pragma unroll
        for (int m = 0; m < 4; ++m)
#pragma unroll
        for (int n = 0; n < 4; ++n) {
            int col = wid * 64 + n * 16 + arow;
            float bias = b1[col];
#pragma unroll
            for (int r = 0; r < 4; ++r) {
                int row = m * 16 + (lane >> 4) * 4 + r;
                *(bhalf*)(Yb + yadr(row, 2 * col)) = f2b(fmaxf(acc[m][n][r] + bias, 0.f));
                acc[m][n][r] = 0.f;
            }
        }
        __syncthreads();
        // ---- layer 2: K=256, 8 chunks ----
        for (int kc = 0; kc < 8; ++kc) {
            __syncthreads();
            stageB<4>(W2T, 512, kc * 64, SB, t);
            __syncthreads();
            short8 a[4], b[4];
#pragma unroll
            for (int m = 0; m < 4; ++m)
                a[m] = *(const short8*)(Yb + yadr(m * 16 + arow, kc * 64 + koff));
#pragma unroll
            for (int n = 0; n < 4; ++n)
                b[n] = *(const short8*)(SB + sadr(wid * 64 + n * 16 + arow, koff));
#pragma unroll
            for (int m = 0; m < 4; ++m)
#pragma unroll
                for (int n = 0; n < 4; ++n)
                    acc[m][n] = __builtin_amdgcn_mfma_f32_16x16x32_bf16(a[m], b[n], acc[m][n], 0, 0, 0);
        }
        __syncthreads();
        // epi 2: bias+relu -> Y
#pragma unroll
        for (int m = 0; m < 4; ++m)
#pragma unroll
        for (int n = 0; n < 4; ++n) {
            int col = wid * 64 + n * 16 + arow;
            float bias = b2[col];
#pragma unroll
            for (int r = 0; r < 4; ++r) {
                int row = m * 16 + (lane >> 4) * 4 + r;
                *(bhalf*)(Yb + yadr(row, 2 * col)) = f2b(fmaxf(acc[m][n][r] + bias, 0.f));
            }
        }
        __syncthreads();
        // ---- layer 3: MFMA, wave w owns rows w*16..w*16+15 ----
        f32x4 z;
#pragma unroll
        for (int r = 0; r < 4; ++r) z[r] = 0.f;
        const int col3 = arow;
        for (int kc = 0; kc < 8; ++kc) {
            short8 a3 = *(const short8*)(Yb + yadr(wid * 16 + arow, kc * 64 + koff));
            short8 bw;
#pragma unroll
            for (int j = 0; j < 8; ++j) bw[j] = 0;
            if (col3 < DOUT) {
                int kb = kc * 32 + (lane >> 4) * 8;
#pragma unroll
                for (int j = 0; j < 8; ++j)
                    bw[j] = (short)f2b(W3[(kb + j) * DOUT + col3]);
            }
            z = __builtin_amdgcn_mfma_f32_16x16x32_bf16(a3, bw, z, 0, 0, 0);
        }
        if (col3 < DOUT) {
            float bias = b3[col3];
#pragma unroll
            for (int rr = 0; rr < 4; ++rr) {
                int r = wid * 16 + (lane >> 4) * 4 + rr;
                int p2 = tstart + r;
                if ((p2 - gbase) < gcnt) {
                    int ro = perm[p2];
                    float v = z[rr] + bias;
                    if (head == 0) out[(size_t)ro * 3 + col3] = 1.f / (1.f + __expf(-v));
                    else           out[(size_t)NB * 3 + ro] = v;
                }
            }
        }
    }
}

extern "C" void kernel_launch(void* const* d_in, const int* in_sizes, int n_in,
                              void* d_out, int out_size, void* d_ws, size_t ws_size,
                              hipStream_t stream) {
    (void)in_sizes; (void)n_in; (void)out_size; (void)ws_size;
    const float* emb   = (const float*)d_in[0];
    const float* speed = (const float*)d_in[1];
    const int*   cmd   = (const int*)d_in[2];
    const float* Wsi1  = (const float*)d_in[3];
    const float* bsi1  = (const float*)d_in[4];
    const float* Wsi2  = (const float*)d_in[5];
    const float* bsi2  = (const float*)d_in[6];
    const float* Wso1  = (const float*)d_in[7];
    const float* bso1  = (const float*)d_in[8];
    const float* Wso2  = (const float*)d_in[9];
    const float* bso2  = (const float*)d_in[10];
    const float* Wso3  = (const float*)d_in[11];
    const float* bso3  = (const float*)d_in[12];
    const float* Wb1   = (const float*)d_in[13];
    const float* bb1   = (const float*)d_in[14];
    const float* Wb2   = (const float*)d_in[15];
    const float* bb2   = (const float*)d_in[16];
    const float* Wb3   = (const float*)d_in[17];
    const float* bb3   = (const float*)d_in[18];
    float* out = (float*)d_out;

    char* ws = (char*)d_ws;
    int*   perm  = (int*)(ws);
    int*   cnt   = (int*)(ws + 263680);
    bhalf* Wsi2T = (bhalf*)(ws + 264192);
    bhalf* Wso1T = (bhalf*)(ws + 329728);
    bhalf* Wso2T = (bhalf*)(ws + 657408);
    bhalf* Wb1T  = (bhalf*)(ws + 788480);
    bhalf* Wb2T  = (bhalf*)(ws + 2754560);

    k_wprep<<<400, 256, 0, stream>>>(Wsi2, Wso1, Wso2, Wb1, Wb2,
                                     Wsi2T, Wso1T, Wso2T, Wb1T, Wb2T, cnt);
    k_hist<<<NB / 256, 256, 0, stream>>>(cmd, cnt);
    k_scan<<<1, 1, 0, stream>>>(cnt);
    k_scatter<<<NB / 256, 256, 0, stream>>>(cmd, cnt, perm);
    k_head<<<NGRID, 256, 0, stream>>>(emb, speed, Wsi1, bsi1, Wsi2T, bsi2,
                                      Wso1T, bso1, Wso2T, bso2, Wso3, bso3,
                                      Wb1T, bb1, Wb2T, bb2, Wb3, bb3,
                                      cnt, perm, out);
}

// Round 4
// 312.241 us; speedup vs baseline: 1.2973x; 1.2973x over previous
//
#include <hip/hip_runtime.h>
#include <hip/hip_bf16.h>

// CILRS head, MI355X round 4.
// Round-2 proven geometry (separate branch/speed block regions, spb from
// k_prep, 84-VGPR no-spill budget) + T14 async register staging: weight tile
// kc+1 is loaded global->reg while kc's MFMA runs, written reg->LDS after the
// barrier. Removes the vmcnt(0)-drain latency from the per-section critical
// path (round-2 was latency-bound: Mfma 17%, HBM 14%, occ 30%).
// ws layout (bytes):
//   0        spb    : B*128 bf16 sp-latent (16,777,216)
//   16777216 perm   : (B+384) int32
//   17040896 cnt    : 20 ints (cnt[6], spare[7], ctr2[6])
//   17041152 Wsi2T  : [128][256] bf16
//   17106688 Wso1T  : [256][640] bf16
//   17434368 Wso2T  : [256][256] bf16
//   17565440 Wb1T   : [6][256][640] bf16
//   19531520 Wb2T   : [6][256][256] bf16  (end 20,317,952)

#define NB 65536
#define NBRB 1030   // branch-region blocks; speed region follows

typedef __attribute__((ext_vector_type(8))) short short8;
typedef __attribute__((ext_vector_type(4))) float f32x4;
typedef unsigned short bhalf;
typedef unsigned int u32;

__device__ __forceinline__ bhalf f2b(float x) {
    __hip_bfloat16 h = __float2bfloat16(x);
    return *reinterpret_cast<bhalf*>(&h);
}
__device__ __forceinline__ float b2f(bhalf u) {
    union { u32 u; float f; } v; v.u = ((u32)u) << 16;
    return v.f;
}
// 64B-row tiles (SA/SB): phys = row*64 + (cb ^ (((row>>1)&3)<<4))
__device__ __forceinline__ int sadr(int row, int cb) {
    return row * 64 + (cb ^ (((row >> 1) & 3) << 4));
}
// 512B-row tile (Y): phys = row*512 + (cb ^ ((row&7)<<4))
__device__ __forceinline__ int yadr(int row, int cb) {
    return row * 512 + (cb ^ ((row & 7) << 4));
}

// -------- weight transpose, 64x64 LDS tiles, + cnt zeroing --------
__global__ __launch_bounds__(256) void k_wprep(
    const float* __restrict__ Wsi2, const float* __restrict__ Wso1,
    const float* __restrict__ Wso2, const float* __restrict__ Wb1,
    const float* __restrict__ Wb2,
    bhalf* __restrict__ Wsi2T, bhalf* __restrict__ Wso1T,
    bhalf* __restrict__ Wso2T, bhalf* __restrict__ Wb1T,
    bhalf* __restrict__ Wb2T, int* __restrict__ cnt) {
    __shared__ float T[64][65];
    const int id = blockIdx.x, t = threadIdx.x;
    if (id == 0 && t < 20) cnt[t] = 0;
    const float* src; bhalf* dst; int K, N, tk, tn, b;
    if (id < 8)        { src = Wsi2; dst = Wsi2T; K = 256; N = 128; b = 0; int tl = id;      tk = tl / 2; tn = tl % 2; }
    else if (id < 48)  { src = Wso1; dst = Wso1T; K = 640; N = 256; b = 0; int tl = id - 8;  tk = tl / 4; tn = tl % 4; }
    else if (id < 64)  { src = Wso2; dst = Wso2T; K = 256; N = 256; b = 0; int tl = id - 48; tk = tl / 4; tn = tl % 4; }
    else if (id < 304) { src = Wb1;  dst = Wb1T;  K = 640; N = 256; int li = id - 64;  b = li / 40; int tl = li % 40; tk = tl / 4; tn = tl % 4; }
    else               { src = Wb2;  dst = Wb2T;  K = 256; N = 256; int li = id - 304; b = li / 16; int tl = li % 16; tk = tl / 4; tn = tl % 4; }
    const int k0 = tk * 64, n0 = tn * 64;
    src += (size_t)b * K * N; dst += (size_t)b * N * K;
    const int c = t & 63, r0 = t >> 6;
#pragma unroll
    for (int j = 0; j < 16; ++j) {
        int r = r0 + j * 4;
        T[r][c] = src[(size_t)(k0 + r) * N + n0 + c];
    }
    __syncthreads();
#pragma unroll
    for (int j = 0; j < 16; ++j) {
        int r = r0 + j * 4;
        dst[(size_t)(n0 + r) * K + k0 + c] = f2b(T[c][r]);
    }
}

__global__ void k_hist(const int* __restrict__ cmd, int* __restrict__ cnt) {
    int idx = blockIdx.x * 256 + threadIdx.x;
    int c = cmd[idx] - 1;
    int lane = threadIdx.x & 63;
    for (int g = 0; g < 6; ++g) {
        unsigned long long m = __ballot(c == g);
        if (m && lane == (__ffsll(m) - 1)) atomicAdd(&cnt[g], __popcll(m));
    }
}

// scatter with locally-recomputed padded scan (k_scan dispatch removed)
__global__ void k_scatter(const int* __restrict__ cmd, int* __restrict__ cnt,
                          int* __restrict__ perm) {
    int idx = blockIdx.x * 256 + threadIdx.x;
    int c = cmd[idx] - 1;
    int lane = threadIdx.x & 63;
    int* ctr2 = (int*)cnt + 13;
    int off = 0;
    for (int g = 0; g < 6; ++g) {
        int cg = cnt[g];
        unsigned long long m = __ballot(c == g);
        if (m) {
            int leader = __ffsll(m) - 1;
            int base = 0;
            if (lane == leader) base = atomicAdd(&ctr2[g], __popcll(m));
            base = __shfl(base, leader);
            if (c == g) {
                int pos = base + __popcll(m & ((1ull << lane) - 1ull));
                perm[off + pos] = idx;
            }
        }
        off += ((cg + 63) >> 6) << 6;
    }
}

// speed-latent: sp = relu(speed*Wsi1+bsi1) @ Wsi2 + bsi2, bf16 [B,128]
__global__ __launch_bounds__(256) void k_prep(
    const float* __restrict__ speed, const float* __restrict__ Wsi1,
    const float* __restrict__ bsi1, const bhalf* __restrict__ Wsi2T,
    const float* __restrict__ bsi2, bhalf* __restrict__ spb) {
    __shared__ bhalf A[64 * 72];
    __shared__ bhalf BT[128 * 72];
    const int t = threadIdx.x, lane = t & 63, wid = t >> 6;
    const int rbase = blockIdx.x * 64;
    const int wm = wid >> 1, wn = wid & 1;
    f32x4 acc[2][4];
    for (int m = 0; m < 2; ++m) for (int n = 0; n < 4; ++n)
        for (int r = 0; r < 4; ++r) acc[m][n][r] = 0.f;
    const int ar = t >> 2, kp = (t & 3) * 16;
    const float s = speed[rbase + ar];
    for (int kc = 0; kc < 4; ++kc) {
        short8 w0, w1;
#pragma unroll
        for (int j = 0; j < 8; ++j) {
            int k = kc * 64 + kp + j;
            w0[j] = (short)f2b(fmaxf(fmaf(s, Wsi1[k], bsi1[k]), 0.f));
            w1[j] = (short)f2b(fmaxf(fmaf(s, Wsi1[k + 8], bsi1[k + 8]), 0.f));
        }
        *(short8*)&A[ar * 72 + kp] = w0;
        *(short8*)&A[ar * 72 + kp + 8] = w1;
#pragma unroll
        for (int j = 0; j < 4; ++j) {
            int ch = t + j * 256;
            int n2 = ch >> 3, ko = (ch & 7) * 8;
            *(short8*)&BT[n2 * 72 + ko] =
                *(const short8*)(Wsi2T + n2 * 256 + kc * 64 + ko);
        }
        __syncthreads();
#pragma unroll
        for (int ks = 0; ks < 2; ++ks) {
            short8 a[2], b[4];
#pragma unroll
            for (int m = 0; m < 2; ++m)
                a[m] = *(const short8*)&A[(wm * 32 + m * 16 + (lane & 15)) * 72 + ks * 32 + (lane >> 4) * 8];
#pragma unroll
            for (int n = 0; n < 4; ++n)
                b[n] = *(const short8*)&BT[(wn * 64 + n * 16 + (lane & 15)) * 72 + ks * 32 + (lane >> 4) * 8];
#pragma unroll
            for (int m = 0; m < 2; ++m)
#pragma unroll
                for (int n = 0; n < 4; ++n)
                    acc[m][n] = __builtin_amdgcn_mfma_f32_16x16x32_bf16(a[m], b[n], acc[m][n], 0, 0, 0);
        }
        __syncthreads();
    }
#pragma unroll
    for (int m = 0; m < 2; ++m)
#pragma unroll
    for (int n = 0; n < 4; ++n) {
        int col = wn * 64 + n * 16 + (lane & 15);
        float bias = bsi2[col];
#pragma unroll
        for (int r = 0; r < 4; ++r) {
            int row = rbase + wm * 32 + m * 16 + (lane >> 4) * 4 + r;
            spb[row * 128 + col] = f2b(acc[m][n][r] + bias);
        }
    }
}

// -------- fused 3-layer head, T14 register-staged pipeline --------
__global__ __launch_bounds__(256, 3) void k_head(
    const float* __restrict__ emb, const bhalf* __restrict__ spb,
    const bhalf* __restrict__ Wso1T, const float* __restrict__ bso1,
    const bhalf* __restrict__ Wso2T, const float* __restrict__ bso2,
    const float* __restrict__ Wso3, const float* __restrict__ bso3,
    const bhalf* __restrict__ Wb1T, const float* __restrict__ bb1,
    const bhalf* __restrict__ Wb2T, const float* __restrict__ bb2,
    const float* __restrict__ Wb3, const float* __restrict__ bb3,
    const int* __restrict__ cnt, const int* __restrict__ perm,
    float* __restrict__ out) {
    __shared__ __align__(16) char SA[4096];    // [64 rows][32 k] swz
    __shared__ __align__(16) char SB[16384];   // [256 n][32 k] swz
    __shared__ __align__(16) char Yb[32768];   // [64 rows][256] swz
    const int t = threadIdx.x, lane = t & 63, wid = t >> 6;
    const bool isB = blockIdx.x < NBRB;
    int tstart, DOUT, gcnt, gbase;
    const bhalf *W1T, *W2T; const float *b1, *b2, *W3, *b3;
    if (isB) {
        tstart = blockIdx.x * 64;
        int off = 0, g = -1, gb = 0, gc = 0;
        for (int q = 0; q < 6; ++q) {
            int cq = cnt[q];
            int pq = off;
            off += ((cq + 63) >> 6) << 6;
            if (g < 0 && tstart < off) { g = q; gb = pq; gc = cq; }
        }
        if (g < 0) return;                     // past padded total
        gbase = gb; gcnt = gc;
        W1T = Wb1T + (size_t)g * (256 * 640); b1 = bb1 + g * 256;
        W2T = Wb2T + (size_t)g * (256 * 256); b2 = bb2 + g * 256;
        W3  = Wb3  + (size_t)g * (256 * 3);   b3 = bb3 + g * 3;
        DOUT = 3;
    } else {
        tstart = (blockIdx.x - NBRB) * 64;
        gbase = 0; gcnt = NB;
        W1T = Wso1T; b1 = bso1; W2T = Wso2T; b2 = bso2; W3 = Wso3; b3 = bso3;
        DOUT = 1;
    }
    const int iA = t >> 2;
    const int pA = tstart + iA;
    int rA;
    if (isB) rA = ((pA - gbase) < gcnt) ? perm[pA] : 0;
    else     rA = pA;

    f32x4 acc[4][4];
#pragma unroll
    for (int m = 0; m < 4; ++m)
#pragma unroll
        for (int n = 0; n < 4; ++n)
#pragma unroll
            for (int r = 0; r < 4; ++r) acc[m][n][r] = 0.f;

    const int arow = lane & 15, koff = (lane >> 4) * 16;
    const int sAoff = sadr(iA, (t & 3) * 16);
    // B-staging map (kc-independent): ch = t + j*256, row = ch>>2, cb = (ch&3)*16
    const int brow = (t + 0 * 256) >> 2;        // rows for j=0..3: t>>2, 64+t>>2, ...
    const int bcb = (t & 3) * 16;
    const int wq0 = sadr((t >> 2) + 0,   bcb);
    const int wq1 = sadr((t >> 2) + 64,  bcb);
    const int wq2 = sadr((t >> 2) + 128, bcb);
    const int wq3 = sadr((t >> 2) + 192, bcb);
    (void)brow;

    // staging registers
    float4 nA0, nA1; short8 nSP;
    uint4 nB0, nB1, nB2, nB3;

#define LD_A(KC) do { int kg = (KC) * 32 + (t & 3) * 8;                          \
        if ((KC) < 16) {                                                          \
            nA0 = *(const float4*)(emb + (size_t)rA * 512 + kg);                  \
            nA1 = *(const float4*)(emb + (size_t)rA * 512 + kg + 4);              \
        } else {                                                                  \
            nSP = *(const short8*)(spb + (size_t)rA * 128 + (kg - 512));          \
        } } while (0)
#define LD_B(W, STRIDE, KC) do {                                                  \
        const char* wp_ = (const char*)(W) + (KC) * 64 + bcb;                     \
        nB0 = *(const uint4*)(wp_ + (size_t)((t >> 2) + 0)   * (STRIDE));         \
        nB1 = *(const uint4*)(wp_ + (size_t)((t >> 2) + 64)  * (STRIDE));         \
        nB2 = *(const uint4*)(wp_ + (size_t)((t >> 2) + 128) * (STRIDE));         \
        nB3 = *(const uint4*)(wp_ + (size_t)((t >> 2) + 192) * (STRIDE));         \
    } while (0)

    // ---------------- layer 1: K=640, 20 sections ----------------
    LD_A(0); LD_B(W1T, 1280, 0);
    for (int kc = 0; kc < 20; ++kc) {
        short8 w;
        if (kc < 16) {
            w[0] = (short)f2b(nA0.x); w[1] = (short)f2b(nA0.y);
            w[2] = (short)f2b(nA0.z); w[3] = (short)f2b(nA0.w);
            w[4] = (short)f2b(nA1.x); w[5] = (short)f2b(nA1.y);
            w[6] = (short)f2b(nA1.z); w[7] = (short)f2b(nA1.w);
        } else {
            w = nSP;
        }
        __syncthreads();                        // prior section's ds_reads done
        *(short8*)(SA + sAoff) = w;
        *(uint4*)(SB + wq0) = nB0; *(uint4*)(SB + wq1) = nB1;
        *(uint4*)(SB + wq2) = nB2; *(uint4*)(SB + wq3) = nB3;
        if (kc < 19) {                          // prefetch next section
            int kn = kc + 1;
            LD_A(kn); LD_B(W1T, 1280, kn);
        }
        __syncthreads();
        short8 a[4], b[4];
#pragma unroll
        for (int m = 0; m < 4; ++m)
            a[m] = *(const short8*)(SA + sadr(m * 16 + arow, koff));
#pragma unroll
        for (int n = 0; n < 4; ++n)
            b[n] = *(const short8*)(SB + sadr(wid * 64 + n * 16 + arow, koff));
#pragma unroll
        for (int m = 0; m < 4; ++m)
#pragma unroll
            for (int n = 0; n < 4; ++n)
                acc[m][n] = __builtin_amdgcn_mfma_f32_16x16x32_bf16(a[m], b[n], acc[m][n], 0, 0, 0);
    }
    // epi 1: bias+relu -> Y (Yb untouched during L1: no barrier needed)
#pragma unroll
    for (int m = 0; m < 4; ++m)
#pragma unroll
    for (int n = 0; n < 4; ++n) {
        int col = wid * 64 + n * 16 + arow;
        float bias = b1[col];
#pragma unroll
        for (int r = 0; r < 4; ++r) {
            int row = m * 16 + (lane >> 4) * 4 + r;
            *(bhalf*)(Yb + yadr(row, 2 * col)) = f2b(fmaxf(acc[m][n][r] + bias, 0.f));
            acc[m][n][r] = 0.f;
        }
    }
    // ---------------- layer 2: K=256, 8 sections ----------------
    LD_B(W2T, 512, 0);
    for (int kc = 0; kc < 8; ++kc) {
        __syncthreads();                        // L1 last reads / epi-1 writes done
        *(uint4*)(SB + wq0) = nB0; *(uint4*)(SB + wq1) = nB1;
        *(uint4*)(SB + wq2) = nB2; *(uint4*)(SB + wq3) = nB3;
        if (kc < 7) LD_B(W2T, 512, kc + 1);
        __syncthreads();
        short8 a[4], b[4];
#pragma unroll
        for (int m = 0; m < 4; ++m)
            a[m] = *(const short8*)(Yb + yadr(m * 16 + arow, kc * 64 + koff));
#pragma unroll
        for (int n = 0; n < 4; ++n)
            b[n] = *(const short8*)(SB + sadr(wid * 64 + n * 16 + arow, koff));
#pragma unroll
        for (int m = 0; m < 4; ++m)
#pragma unroll
            for (int n = 0; n < 4; ++n)
                acc[m][n] = __builtin_amdgcn_mfma_f32_16x16x32_bf16(a[m], b[n], acc[m][n], 0, 0, 0);
    }
    __syncthreads();                            // all L2 Yb reads done
    // epi 2: bias+relu -> Y
#pragma unroll
    for (int m = 0; m < 4; ++m)
#pragma unroll
    for (int n = 0; n < 4; ++n) {
        int col = wid * 64 + n * 16 + arow;
        float bias = b2[col];
#pragma unroll
        for (int r = 0; r < 4; ++r) {
            int row = m * 16 + (lane >> 4) * 4 + r;
            *(bhalf*)(Yb + yadr(row, 2 * col)) = f2b(fmaxf(acc[m][n][r] + bias, 0.f));
        }
    }
    __syncthreads();
    // ---------------- layer 3: MFMA, wave w owns rows w*16..w*16+15 ----------
    f32x4 z;
#pragma unroll
    for (int r = 0; r < 4; ++r) z[r] = 0.f;
    const int col3 = arow;
    for (int kc = 0; kc < 8; ++kc) {
        short8 a3 = *(const short8*)(Yb + yadr(wid * 16 + arow, kc * 64 + koff));
        short8 bw;
#pragma unroll
        for (int j = 0; j < 8; ++j) bw[j] = 0;
        if (col3 < DOUT) {
            int kb = kc * 32 + (lane >> 4) * 8;
#pragma unroll
            for (int j = 0; j < 8; ++j)
                bw[j] = (short)f2b(W3[(kb + j) * DOUT + col3]);
        }
        z = __builtin_amdgcn_mfma_f32_16x16x32_bf16(a3, bw, z, 0, 0, 0);
    }
    if (col3 < DOUT) {
        float bias = b3[col3];
#pragma unroll
        for (int rr = 0; rr < 4; ++rr) {
            int r = wid * 16 + (lane >> 4) * 4 + rr;
            int p2 = tstart + r;
            if ((p2 - gbase) < gcnt) {
                float v = z[rr] + bias;
                if (isB) {
                    int ro = perm[p2];
                    out[(size_t)ro * 3 + col3] = 1.f / (1.f + __expf(-v));
                } else {
                    out[(size_t)NB * 3 + p2] = v;
                }
            }
        }
    }
#undef LD_A
#undef LD_B
}

extern "C" void kernel_launch(void* const* d_in, const int* in_sizes, int n_in,
                              void* d_out, int out_size, void* d_ws, size_t ws_size,
                              hipStream_t stream) {
    (void)in_sizes; (void)n_in; (void)out_size; (void)ws_size;
    const float* emb   = (const float*)d_in[0];
    const float* speed = (const float*)d_in[1];
    const int*   cmd   = (const int*)d_in[2];
    const float* Wsi1  = (const float*)d_in[3];
    const float* bsi1  = (const float*)d_in[4];
    const float* Wsi2  = (const float*)d_in[5];
    const float* bsi2  = (const float*)d_in[6];
    const float* Wso1  = (const float*)d_in[7];
    const float* bso1  = (const float*)d_in[8];
    const float* Wso2  = (const float*)d_in[9];
    const float* bso2  = (const float*)d_in[10];
    const float* Wso3  = (const float*)d_in[11];
    const float* bso3  = (const float*)d_in[12];
    const float* Wb1   = (const float*)d_in[13];
    const float* bb1   = (const float*)d_in[14];
    const float* Wb2   = (const float*)d_in[15];
    const float* bb2   = (const float*)d_in[16];
    const float* Wb3   = (const float*)d_in[17];
    const float* bb3   = (const float*)d_in[18];
    float* out = (float*)d_out;

    char* ws = (char*)d_ws;
    bhalf* spb   = (bhalf*)(ws);
    int*   perm  = (int*)(ws + 16777216);
    int*   cnt   = (int*)(ws + 17040896);
    bhalf* Wsi2T = (bhalf*)(ws + 17041152);
    bhalf* Wso1T = (bhalf*)(ws + 17106688);
    bhalf* Wso2T = (bhalf*)(ws + 17434368);
    bhalf* Wb1T  = (bhalf*)(ws + 17565440);
    bhalf* Wb2T  = (bhalf*)(ws + 19531520);

    k_wprep<<<400, 256, 0, stream>>>(Wsi2, Wso1, Wso2, Wb1, Wb2,
                                     Wsi2T, Wso1T, Wso2T, Wb1T, Wb2T, cnt);
    k_prep<<<NB / 64, 256, 0, stream>>>(speed, Wsi1, bsi1, Wsi2T, bsi2, spb);
    k_hist<<<NB / 256, 256, 0, stream>>>(cmd, cnt);
    k_scatter<<<NB / 256, 256, 0, stream>>>(cmd, cnt, perm);
    k_head<<<NBRB + NB / 64, 256, 0, stream>>>(emb, spb,
                                               Wso1T, bso1, Wso2T, bso2, Wso3, bso3,
                                               Wb1T, bb1, Wb2T, bb2, Wb3, bb3,
                                               cnt, perm, out);
}

// Round 5
// 304.195 us; speedup vs baseline: 1.3317x; 1.0264x over previous
//
#include <hip/hip_runtime.h>
#include <hip/hip_bf16.h>

// CILRS head, MI355X round 5.
// Round-2 geometry + T3/T4 pipeline: ALL staging via global_load_lds into
// double-buffered LDS, raw s_barrier + counted inline-asm vmcnt (never 0 in
// the loop). emb staged as f32 (pre-swizzled source), converted to bf16 in
// registers after ds_read. No staging registers held across barriers.
// LDS = SA 2x8K (f32 A) + SB 2x16K (bf16 B) + Y 32K = 81920 B -> 2 blocks/CU.
// ws layout (bytes):
//   0        spb    : B*128 bf16 sp-latent (16,777,216)
//   16777216 perm   : (B+384) int32
//   17040896 cnt    : 20 ints (cnt[6], spare[7], ctr2[6])
//   17041152 Wsi2T  : [128][256] bf16
//   17106688 Wso1T  : [256][640] bf16
//   17434368 Wso2T  : [256][256] bf16
//   17565440 Wb1T   : [6][256][640] bf16
//   19531520 Wb2T   : [6][256][256] bf16  (end 20,317,952)

#define NB 65536
#define NBRB 1030   // branch-region blocks; speed region follows

typedef __attribute__((ext_vector_type(8))) short short8;
typedef __attribute__((ext_vector_type(4))) float f32x4;
typedef unsigned short bhalf;
typedef unsigned int u32;

__device__ __forceinline__ bhalf f2b(float x) {
    __hip_bfloat16 h = __float2bfloat16(x);
    return *reinterpret_cast<bhalf*>(&h);
}
__device__ __forceinline__ void gll16(const void* g, void* l) {
    __builtin_amdgcn_global_load_lds(
        (const __attribute__((address_space(1))) u32*)g,
        (__attribute__((address_space(3))) u32*)l, 16, 0, 0);
}
// 64B-row bf16 tiles (SB, sp-A): phys = row*64 + (cb ^ (((row>>1)&3)<<4))
__device__ __forceinline__ int sadr(int row, int cb) {
    return row * 64 + (cb ^ (((row >> 1) & 3) << 4));
}
// 512B-row tile (Y): phys = row*512 + (cb ^ ((row&7)<<4))
__device__ __forceinline__ int yadr(int row, int cb) {
    return row * 512 + (cb ^ ((row & 7) << 4));
}
__device__ __forceinline__ void wvm6() { asm volatile("s_waitcnt vmcnt(6)" ::: "memory"); }
__device__ __forceinline__ void wvm4() { asm volatile("s_waitcnt vmcnt(4)" ::: "memory"); }
__device__ __forceinline__ void wvm0() { asm volatile("s_waitcnt vmcnt(0)" ::: "memory"); }
__device__ __forceinline__ void wlgkm0() { asm volatile("s_waitcnt lgkmcnt(0)" ::: "memory"); }

// -------- weight transpose, 64x64 LDS tiles, + cnt zeroing --------
__global__ __launch_bounds__(256) void k_wprep(
    const float* __restrict__ Wsi2, const float* __restrict__ Wso1,
    const float* __restrict__ Wso2, const float* __restrict__ Wb1,
    const float* __restrict__ Wb2,
    bhalf* __restrict__ Wsi2T, bhalf* __restrict__ Wso1T,
    bhalf* __restrict__ Wso2T, bhalf* __restrict__ Wb1T,
    bhalf* __restrict__ Wb2T, int* __restrict__ cnt) {
    __shared__ float T[64][65];
    const int id = blockIdx.x, t = threadIdx.x;
    if (id == 0 && t < 20) cnt[t] = 0;
    const float* src; bhalf* dst; int K, N, tk, tn, b;
    if (id < 8)        { src = Wsi2; dst = Wsi2T; K = 256; N = 128; b = 0; int tl = id;      tk = tl / 2; tn = tl % 2; }
    else if (id < 48)  { src = Wso1; dst = Wso1T; K = 640; N = 256; b = 0; int tl = id - 8;  tk = tl / 4; tn = tl % 4; }
    else if (id < 64)  { src = Wso2; dst = Wso2T; K = 256; N = 256; b = 0; int tl = id - 48; tk = tl / 4; tn = tl % 4; }
    else if (id < 304) { src = Wb1;  dst = Wb1T;  K = 640; N = 256; int li = id - 64;  b = li / 40; int tl = li % 40; tk = tl / 4; tn = tl % 4; }
    else               { src = Wb2;  dst = Wb2T;  K = 256; N = 256; int li = id - 304; b = li / 16; int tl = li % 16; tk = tl / 4; tn = tl % 4; }
    const int k0 = tk * 64, n0 = tn * 64;
    src += (size_t)b * K * N; dst += (size_t)b * N * K;
    const int c = t & 63, r0 = t >> 6;
#pragma unroll
    for (int j = 0; j < 16; ++j) {
        int r = r0 + j * 4;
        T[r][c] = src[(size_t)(k0 + r) * N + n0 + c];
    }
    __syncthreads();
#pragma unroll
    for (int j = 0; j < 16; ++j) {
        int r = r0 + j * 4;
        dst[(size_t)(n0 + r) * K + k0 + c] = f2b(T[c][r]);
    }
}

__global__ void k_hist(const int* __restrict__ cmd, int* __restrict__ cnt) {
    int idx = blockIdx.x * 256 + threadIdx.x;
    int c = cmd[idx] - 1;
    int lane = threadIdx.x & 63;
    for (int g = 0; g < 6; ++g) {
        unsigned long long m = __ballot(c == g);
        if (m && lane == (__ffsll(m) - 1)) atomicAdd(&cnt[g], __popcll(m));
    }
}

// scatter with locally-recomputed padded scan
__global__ void k_scatter(const int* __restrict__ cmd, int* __restrict__ cnt,
                          int* __restrict__ perm) {
    int idx = blockIdx.x * 256 + threadIdx.x;
    int c = cmd[idx] - 1;
    int lane = threadIdx.x & 63;
    int* ctr2 = (int*)cnt + 13;
    int off = 0;
    for (int g = 0; g < 6; ++g) {
        int cg = cnt[g];
        unsigned long long m = __ballot(c == g);
        if (m) {
            int leader = __ffsll(m) - 1;
            int base = 0;
            if (lane == leader) base = atomicAdd(&ctr2[g], __popcll(m));
            base = __shfl(base, leader);
            if (c == g) {
                int pos = base + __popcll(m & ((1ull << lane) - 1ull));
                perm[off + pos] = idx;
            }
        }
        off += ((cg + 63) >> 6) << 6;
    }
}

// speed-latent: sp = relu(speed*Wsi1+bsi1) @ Wsi2 + bsi2, bf16 [B,128]
__global__ __launch_bounds__(256) void k_prep(
    const float* __restrict__ speed, const float* __restrict__ Wsi1,
    const float* __restrict__ bsi1, const bhalf* __restrict__ Wsi2T,
    const float* __restrict__ bsi2, bhalf* __restrict__ spb) {
    __shared__ bhalf A[64 * 72];
    __shared__ bhalf BT[128 * 72];
    const int t = threadIdx.x, lane = t & 63, wid = t >> 6;
    const int rbase = blockIdx.x * 64;
    const int wm = wid >> 1, wn = wid & 1;
    f32x4 acc[2][4];
    for (int m = 0; m < 2; ++m) for (int n = 0; n < 4; ++n)
        for (int r = 0; r < 4; ++r) acc[m][n][r] = 0.f;
    const int ar = t >> 2, kp = (t & 3) * 16;
    const float s = speed[rbase + ar];
    for (int kc = 0; kc < 4; ++kc) {
        short8 w0, w1;
#pragma unroll
        for (int j = 0; j < 8; ++j) {
            int k = kc * 64 + kp + j;
            w0[j] = (short)f2b(fmaxf(fmaf(s, Wsi1[k], bsi1[k]), 0.f));
            w1[j] = (short)f2b(fmaxf(fmaf(s, Wsi1[k + 8], bsi1[k + 8]), 0.f));
        }
        *(short8*)&A[ar * 72 + kp] = w0;
        *(short8*)&A[ar * 72 + kp + 8] = w1;
#pragma unroll
        for (int j = 0; j < 4; ++j) {
            int ch = t + j * 256;
            int n2 = ch >> 3, ko = (ch & 7) * 8;
            *(short8*)&BT[n2 * 72 + ko] =
                *(const short8*)(Wsi2T + n2 * 256 + kc * 64 + ko);
        }
        __syncthreads();
#pragma unroll
        for (int ks = 0; ks < 2; ++ks) {
            short8 a[2], b[4];
#pragma unroll
            for (int m = 0; m < 2; ++m)
                a[m] = *(const short8*)&A[(wm * 32 + m * 16 + (lane & 15)) * 72 + ks * 32 + (lane >> 4) * 8];
#pragma unroll
            for (int n = 0; n < 4; ++n)
                b[n] = *(const short8*)&BT[(wn * 64 + n * 16 + (lane & 15)) * 72 + ks * 32 + (lane >> 4) * 8];
#pragma unroll
            for (int m = 0; m < 2; ++m)
#pragma unroll
                for (int n = 0; n < 4; ++n)
                    acc[m][n] = __builtin_amdgcn_mfma_f32_16x16x32_bf16(a[m], b[n], acc[m][n], 0, 0, 0);
        }
        __syncthreads();
    }
#pragma unroll
    for (int m = 0; m < 2; ++m)
#pragma unroll
    for (int n = 0; n < 4; ++n) {
        int col = wn * 64 + n * 16 + (lane & 15);
        float bias = bsi2[col];
#pragma unroll
        for (int r = 0; r < 4; ++r) {
            int row = rbase + wm * 32 + m * 16 + (lane >> 4) * 4 + r;
            spb[row * 128 + col] = f2b(acc[m][n][r] + bias);
        }
    }
}

// -------- fused 3-layer head, counted-vmcnt double-buffered pipeline --------
__global__ __launch_bounds__(256, 2) void k_head(
    const float* __restrict__ emb, const bhalf* __restrict__ spb,
    const bhalf* __restrict__ Wso1T, const float* __restrict__ bso1,
    const bhalf* __restrict__ Wso2T, const float* __restrict__ bso2,
    const float* __restrict__ Wso3, const float* __restrict__ bso3,
    const bhalf* __restrict__ Wb1T, const float* __restrict__ bb1,
    const bhalf* __restrict__ Wb2T, const float* __restrict__ bb2,
    const float* __restrict__ Wb3, const float* __restrict__ bb3,
    const int* __restrict__ cnt, const int* __restrict__ perm,
    float* __restrict__ out) {
    __shared__ __align__(16) char SA[2][8192];    // f32 A tile [64 rows][32 k] (or bf16 sp in lower 4K)
    __shared__ __align__(16) char SB[2][16384];   // bf16 B tile [256 n][32 k] swz
    __shared__ __align__(16) char Yb[32768];      // bf16 Y [64 rows][256] swz
    const int t = threadIdx.x, lane = t & 63, wid = t >> 6;
    const bool isB = blockIdx.x < NBRB;
    int tstart, DOUT, gcnt, gbase;
    const bhalf *W1T, *W2T; const float *b1, *b2, *W3, *b3;
    if (isB) {
        tstart = blockIdx.x * 64;
        int off = 0, g = -1, gb = 0, gc = 0;
        for (int q = 0; q < 6; ++q) {
            int cq = cnt[q];
            int pq = off;
            off += ((cq + 63) >> 6) << 6;
            if (g < 0 && tstart < off) { g = q; gb = pq; gc = cq; }
        }
        if (g < 0) return;                     // uniform early-out (no barriers yet)
        gbase = gb; gcnt = gc;
        W1T = Wb1T + (size_t)g * (256 * 640); b1 = bb1 + g * 256;
        W2T = Wb2T + (size_t)g * (256 * 256); b2 = bb2 + g * 256;
        W3  = Wb3  + (size_t)g * (256 * 3);   b3 = bb3 + g * 3;
        DOUT = 3;
    } else {
        tstart = (blockIdx.x - NBRB) * 64;
        gbase = 0; gcnt = NB;
        W1T = Wso1T; b1 = bso1; W2T = Wso2T; b2 = bso2; W3 = Wso3; b3 = bso3;
        DOUT = 1;
    }

    // per-thread source rows for the gll staging maps
    //  A-f32: p = t*16 + j*4096 -> row = (t>>3)+j*32, cb = (t&7)*16
    //  A-sp / B: p = t*16 (+j*4096) -> row = (t>>2)(+j*64), cb = (t&3)*16
    const int rowA0 = t >> 3, rowA1 = rowA0 + 32;
    const int rowS  = t >> 2;
    int ra0, ra1, raS;
    if (isB) {
        int p0 = tstart + rowA0, p1 = tstart + rowA1, pS = tstart + rowS;
        ra0 = ((p0 - gbase) < gcnt) ? perm[p0] : 0;
        ra1 = ((p1 - gbase) < gcnt) ? perm[p1] : 0;
        raS = ((pS - gbase) < gcnt) ? perm[pS] : 0;
    } else {
        ra0 = tstart + rowA0; ra1 = tstart + rowA1; raS = tstart + rowS;
    }
    const int lcA0 = ((t & 7) * 16) ^ ((rowA0 & 7) << 4);
    const int lcA1 = ((t & 7) * 16) ^ ((rowA1 & 7) << 4);
    const int lcS  = ((t & 3) * 16) ^ (((rowS >> 1) & 3) << 4);
    const char* embp0 = (const char*)(emb + (size_t)ra0 * 512);
    const char* embp1 = (const char*)(emb + (size_t)ra1 * 512);
    const char* spbp  = (const char*)(spb + (size_t)raS * 128);
    const int dstA = t * 16;   // linear LDS dest offsets
    // B staging rows
    const int rB = t >> 2, cB = (t & 3) * 16;

#define ST_A(KN, BUF) do { int kn_ = (KN);                                       \
        if (kn_ < 16) {                                                           \
            gll16(embp0 + kn_ * 128 + lcA0, SA[BUF] + dstA);                      \
            gll16(embp1 + kn_ * 128 + lcA1, SA[BUF] + dstA + 4096);               \
        } else {                                                                  \
            gll16(spbp + (kn_ - 16) * 64 + lcS, SA[BUF] + dstA);                  \
            gll16(spbp + (kn_ - 16) * 64 + lcS, SA[BUF] + dstA + 4096);           \
        } } while (0)
#define ST_B(W, STRIDE, KB, BUF) do {                                             \
        _Pragma("unroll")                                                         \
        for (int j_ = 0; j_ < 4; ++j_) {                                          \
            int row_ = rB + j_ * 64;                                              \
            int p_ = row_ * 64 + cB;                                              \
            int lc_ = (p_ & 63) ^ (((row_ >> 1) & 3) << 4);                       \
            gll16((const char*)(W) + (size_t)row_ * (STRIDE) + (KB) + lc_,        \
                  SB[BUF] + p_);                                                  \
        } } while (0)

    const int arow = lane & 15, koff = (lane >> 4) * 16;
    // preload biases (avoid mid-stream vmcnt drains)
    float bi1[4], bi2[4];
#pragma unroll
    for (int n = 0; n < 4; ++n) {
        bi1[n] = b1[wid * 64 + n * 16 + arow];
        bi2[n] = b2[wid * 64 + n * 16 + arow];
    }

    f32x4 acc[4][4];
#pragma unroll
    for (int m = 0; m < 4; ++m)
#pragma unroll
        for (int n = 0; n < 4; ++n)
#pragma unroll
            for (int r = 0; r < 4; ++r) acc[m][n][r] = 0.f;

    // ---------------- layer 1: K=640, 20 sections, 2-deep pipeline ----------
    ST_A(0, 0); ST_B(W1T, 1280, 0, 0);          // 6 outstanding
    int cur = 0;
    for (int kc = 0; kc < 20; ++kc) {
        if (kc < 19) { ST_A(kc + 1, cur ^ 1); ST_B(W1T, 1280, (kc + 1) * 64, cur ^ 1); wvm6(); }
        else         { ST_B(W2T, 512, 0, cur ^ 1); wvm4(); }
        __builtin_amdgcn_s_barrier();
        const char* SAc = SA[cur]; const char* SBc = SB[cur];
        short8 a[4], b[4];
#pragma unroll
        for (int n = 0; n < 4; ++n)
            b[n] = *(const short8*)(SBc + sadr(wid * 64 + n * 16 + arow, koff));
        if (kc < 16) {
#pragma unroll
            for (int m = 0; m < 4; ++m) {
                int row = m * 16 + arow;
                int sw = (row & 7) << 4;
                int c0 = (lane >> 4) * 32;
                float4 f0 = *(const float4*)(SAc + row * 128 + (c0 ^ sw));
                float4 f1 = *(const float4*)(SAc + row * 128 + ((c0 + 16) ^ sw));
                a[m][0] = (short)f2b(f0.x); a[m][1] = (short)f2b(f0.y);
                a[m][2] = (short)f2b(f0.z); a[m][3] = (short)f2b(f0.w);
                a[m][4] = (short)f2b(f1.x); a[m][5] = (short)f2b(f1.y);
                a[m][6] = (short)f2b(f1.z); a[m][7] = (short)f2b(f1.w);
            }
        } else {
#pragma unroll
            for (int m = 0; m < 4; ++m)
                a[m] = *(const short8*)(SAc + sadr(m * 16 + arow, koff));
        }
#pragma unroll
        for (int m = 0; m < 4; ++m)
#pragma unroll
            for (int n = 0; n < 4; ++n)
                acc[m][n] = __builtin_amdgcn_mfma_f32_16x16x32_bf16(a[m], b[n], acc[m][n], 0, 0, 0);
        __builtin_amdgcn_s_barrier();
        cur ^= 1;
    }
    // epi 1: bias+relu -> Y
#pragma unroll
    for (int m = 0; m < 4; ++m)
#pragma unroll
    for (int n = 0; n < 4; ++n) {
        int col = wid * 64 + n * 16 + arow;
#pragma unroll
        for (int r = 0; r < 4; ++r) {
            int row = m * 16 + (lane >> 4) * 4 + r;
            *(bhalf*)(Yb + yadr(row, 2 * col)) = f2b(fmaxf(acc[m][n][r] + bi1[n], 0.f));
            acc[m][n][r] = 0.f;
        }
    }
    wlgkm0();
    __builtin_amdgcn_s_barrier();
    // ---------------- layer 2: K=256, 8 sections ----------------------------
    // after 20 flips cur==0; L2 sec0 was staged into SB[0] at kc=19.
    for (int kc = 0; kc < 8; ++kc) {
        if (kc < 7) { ST_B(W2T, 512, (kc + 1) * 64, cur ^ 1); wvm4(); }
        else        { wvm0(); }
        __builtin_amdgcn_s_barrier();
        const char* SBc = SB[cur];
        short8 a[4], b[4];
#pragma unroll
        for (int m = 0; m < 4; ++m)
            a[m] = *(const short8*)(Yb + yadr(m * 16 + arow, kc * 64 + koff));
#pragma unroll
        for (int n = 0; n < 4; ++n)
            b[n] = *(const short8*)(SBc + sadr(wid * 64 + n * 16 + arow, koff));
#pragma unroll
        for (int m = 0; m < 4; ++m)
#pragma unroll
            for (int n = 0; n < 4; ++n)
                acc[m][n] = __builtin_amdgcn_mfma_f32_16x16x32_bf16(a[m], b[n], acc[m][n], 0, 0, 0);
        __builtin_amdgcn_s_barrier();
        cur ^= 1;
    }
    // epi 2: bias+relu -> Y (all L2 Y-reads completed before each wave's MFMA,
    // and the loop-end barrier orders cross-wave)
#pragma unroll
    for (int m = 0; m < 4; ++m)
#pragma unroll
    for (int n = 0; n < 4; ++n) {
        int col = wid * 64 + n * 16 + arow;
#pragma unroll
        for (int r = 0; r < 4; ++r) {
            int row = m * 16 + (lane >> 4) * 4 + r;
            *(bhalf*)(Yb + yadr(row, 2 * col)) = f2b(fmaxf(acc[m][n][r] + bi2[n], 0.f));
        }
    }
    wlgkm0();
    __builtin_amdgcn_s_barrier();
    // ---------------- layer 3: MFMA, wave w owns rows w*16..w*16+15 ----------
    f32x4 z;
#pragma unroll
    for (int r = 0; r < 4; ++r) z[r] = 0.f;
    const int col3 = arow;
    for (int kc = 0; kc < 8; ++kc) {
        short8 a3 = *(const short8*)(Yb + yadr(wid * 16 + arow, kc * 64 + koff));
        short8 bw;
#pragma unroll
        for (int j = 0; j < 8; ++j) bw[j] = 0;
        if (col3 < DOUT) {
            int kb = kc * 32 + (lane >> 4) * 8;
#pragma unroll
            for (int j = 0; j < 8; ++j)
                bw[j] = (short)f2b(W3[(kb + j) * DOUT + col3]);
        }
        z = __builtin_amdgcn_mfma_f32_16x16x32_bf16(a3, bw, z, 0, 0, 0);
    }
    if (col3 < DOUT) {
        float bias = b3[col3];
#pragma unroll
        for (int rr = 0; rr < 4; ++rr) {
            int r = wid * 16 + (lane >> 4) * 4 + rr;
            int p2 = tstart + r;
            if ((p2 - gbase) < gcnt) {
                float v = z[rr] + bias;
                if (isB) {
                    int ro = perm[p2];
                    out[(size_t)ro * 3 + col3] = 1.f / (1.f + __expf(-v));
                } else {
                    out[(size_t)NB * 3 + p2] = v;
                }
            }
        }
    }
#undef ST_A
#undef ST_B
}

extern "C" void kernel_launch(void* const* d_in, const int* in_sizes, int n_in,
                              void* d_out, int out_size, void* d_ws, size_t ws_size,
                              hipStream_t stream) {
    (void)in_sizes; (void)n_in; (void)out_size; (void)ws_size;
    const float* emb   = (const float*)d_in[0];
    const float* speed = (const float*)d_in[1];
    const int*   cmd   = (const int*)d_in[2];
    const float* Wsi1  = (const float*)d_in[3];
    const float* bsi1  = (const float*)d_in[4];
    const float* Wsi2  = (const float*)d_in[5];
    const float* bsi2  = (const float*)d_in[6];
    const float* Wso1  = (const float*)d_in[7];
    const float* bso1  = (const float*)d_in[8];
    const float* Wso2  = (const float*)d_in[9];
    const float* bso2  = (const float*)d_in[10];
    const float* Wso3  = (const float*)d_in[11];
    const float* bso3  = (const float*)d_in[12];
    const float* Wb1   = (const float*)d_in[13];
    const float* bb1   = (const float*)d_in[14];
    const float* Wb2   = (const float*)d_in[15];
    const float* bb2   = (const float*)d_in[16];
    const float* Wb3   = (const float*)d_in[17];
    const float* bb3   = (const float*)d_in[18];
    float* out = (float*)d_out;

    char* ws = (char*)d_ws;
    bhalf* spb   = (bhalf*)(ws);
    int*   perm  = (int*)(ws + 16777216);
    int*   cnt   = (int*)(ws + 17040896);
    bhalf* Wsi2T = (bhalf*)(ws + 17041152);
    bhalf* Wso1T = (bhalf*)(ws + 17106688);
    bhalf* Wso2T = (bhalf*)(ws + 17434368);
    bhalf* Wb1T  = (bhalf*)(ws + 17565440);
    bhalf* Wb2T  = (bhalf*)(ws + 19531520);

    k_wprep<<<400, 256, 0, stream>>>(Wsi2, Wso1, Wso2, Wb1, Wb2,
                                     Wsi2T, Wso1T, Wso2T, Wb1T, Wb2T, cnt);
    k_prep<<<NB / 64, 256, 0, stream>>>(speed, Wsi1, bsi1, Wsi2T, bsi2, spb);
    k_hist<<<NB / 256, 256, 0, stream>>>(cmd, cnt);
    k_scatter<<<NB / 256, 256, 0, stream>>>(cmd, cnt, perm);
    k_head<<<NBRB + NB / 64, 256, 0, stream>>>(emb, spb,
                                               Wso1T, bso1, Wso2T, bso2, Wso3, bso3,
                                               Wb1T, bb1, Wb2T, bb2, Wb3, bb3,
                                               cnt, perm, out);
}

// Round 6
// 155.695 us; speedup vs baseline: 2.6018x; 1.9538x over previous
//
#include <hip/hip_runtime.h>
#include <hip/hip_bf16.h>

// CILRS head, MI355X round 6.
// k_head: round-5 counted-vmcnt L1 pipeline, but LDS overlaid to 49,152 B
// (SB-dbuf region becomes Y after L1; SA-dbuf region becomes L2's single
// B-buffer) -> 3 blocks/CU. L2 serial-staged (weights L2-hot).
// Grouping made atomic-free: per-chunk ballot counts (k_prep) -> 1-block
// scan -> deterministic scatter. No global atomics anywhere.
// ws layout (bytes):
//   0        spb      : B*128 bf16 sp-latent (16,777,216)
//   16777216 perm     : (B+384) int32                 -> 17,040,896
//   17040896 bcnt     : [1024][6] int                 -> 17,065,472
//   17065472 chunkoff : [1024][6] int                 -> 17,090,048
//   17090048 pad      : pad[0..6]=offsets, pad[8+g]=totals (64 ints)
//   17090304 Wsi2T    : [128][256] bf16
//   17155840 Wso1T    : [256][640] bf16
//   17483520 Wso2T    : [256][256] bf16
//   17614592 Wb1T     : [6][256][640] bf16
//   19580672 Wb2T     : [6][256][256] bf16  (end 20,367,104)

#define NB 65536
#define NBRB 1030   // branch-region blocks; speed region follows

typedef __attribute__((ext_vector_type(8))) short short8;
typedef __attribute__((ext_vector_type(4))) float f32x4;
typedef unsigned short bhalf;
typedef unsigned int u32;

__device__ __forceinline__ bhalf f2b(float x) {
    __hip_bfloat16 h = __float2bfloat16(x);
    return *reinterpret_cast<bhalf*>(&h);
}
__device__ __forceinline__ void gll16(const void* g, void* l) {
    __builtin_amdgcn_global_load_lds(
        (const __attribute__((address_space(1))) u32*)g,
        (__attribute__((address_space(3))) u32*)l, 16, 0, 0);
}
// 64B-row bf16 tiles (SB, sp-A): phys = row*64 + (cb ^ (((row>>1)&3)<<4))
__device__ __forceinline__ int sadr(int row, int cb) {
    return row * 64 + (cb ^ (((row >> 1) & 3) << 4));
}
// 512B-row tile (Y): phys = row*512 + (cb ^ ((row&7)<<4))
__device__ __forceinline__ int yadr(int row, int cb) {
    return row * 512 + (cb ^ ((row & 7) << 4));
}
__device__ __forceinline__ void wvm6() { asm volatile("s_waitcnt vmcnt(6)" ::: "memory"); }
__device__ __forceinline__ void wvm0() { asm volatile("s_waitcnt vmcnt(0)" ::: "memory"); }
__device__ __forceinline__ void wlgkm0() { asm volatile("s_waitcnt lgkmcnt(0)" ::: "memory"); }

// -------- weight transpose, 64x64 LDS tiles --------
__global__ __launch_bounds__(256) void k_wprep(
    const float* __restrict__ Wsi2, const float* __restrict__ Wso1,
    const float* __restrict__ Wso2, const float* __restrict__ Wb1,
    const float* __restrict__ Wb2,
    bhalf* __restrict__ Wsi2T, bhalf* __restrict__ Wso1T,
    bhalf* __restrict__ Wso2T, bhalf* __restrict__ Wb1T,
    bhalf* __restrict__ Wb2T) {
    __shared__ float T[64][65];
    const int id = blockIdx.x, t = threadIdx.x;
    const float* src; bhalf* dst; int K, N, tk, tn, b;
    if (id < 8)        { src = Wsi2; dst = Wsi2T; K = 256; N = 128; b = 0; int tl = id;      tk = tl / 2; tn = tl % 2; }
    else if (id < 48)  { src = Wso1; dst = Wso1T; K = 640; N = 256; b = 0; int tl = id - 8;  tk = tl / 4; tn = tl % 4; }
    else if (id < 64)  { src = Wso2; dst = Wso2T; K = 256; N = 256; b = 0; int tl = id - 48; tk = tl / 4; tn = tl % 4; }
    else if (id < 304) { src = Wb1;  dst = Wb1T;  K = 640; N = 256; int li = id - 64;  b = li / 40; int tl = li % 40; tk = tl / 4; tn = tl % 4; }
    else               { src = Wb2;  dst = Wb2T;  K = 256; N = 256; int li = id - 304; b = li / 16; int tl = li % 16; tk = tl / 4; tn = tl % 4; }
    const int k0 = tk * 64, n0 = tn * 64;
    src += (size_t)b * K * N; dst += (size_t)b * N * K;
    const int c = t & 63, r0 = t >> 6;
#pragma unroll
    for (int j = 0; j < 16; ++j) {
        int r = r0 + j * 4;
        T[r][c] = src[(size_t)(k0 + r) * N + n0 + c];
    }
    __syncthreads();
#pragma unroll
    for (int j = 0; j < 16; ++j) {
        int r = r0 + j * 4;
        dst[(size_t)(n0 + r) * K + k0 + c] = f2b(T[c][r]);
    }
}

// speed-latent + per-chunk command counts (NO atomics)
__global__ __launch_bounds__(256) void k_prep(
    const float* __restrict__ speed, const float* __restrict__ Wsi1,
    const float* __restrict__ bsi1, const bhalf* __restrict__ Wsi2T,
    const float* __restrict__ bsi2, const int* __restrict__ cmd,
    bhalf* __restrict__ spb, int* __restrict__ bcnt) {
    __shared__ bhalf A[64 * 72];
    __shared__ bhalf BT[128 * 72];
    const int t = threadIdx.x, lane = t & 63, wid = t >> 6;
    const int rbase = blockIdx.x * 64;
    if (wid == 0) {                      // chunk histogram by wave 0
        int c = cmd[rbase + lane] - 1;
        int v = 0;
#pragma unroll
        for (int g = 0; g < 6; ++g) {
            unsigned long long m = __ballot(c == g);
            if (lane == g) v = (int)__popcll(m);
        }
        if (lane < 6) bcnt[blockIdx.x * 6 + lane] = v;
    }
    const int wm = wid >> 1, wn = wid & 1;
    f32x4 acc[2][4];
    for (int m = 0; m < 2; ++m) for (int n = 0; n < 4; ++n)
        for (int r = 0; r < 4; ++r) acc[m][n][r] = 0.f;
    const int ar = t >> 2, kp = (t & 3) * 16;
    const float s = speed[rbase + ar];
    for (int kc = 0; kc < 4; ++kc) {
        short8 w0, w1;
#pragma unroll
        for (int j = 0; j < 8; ++j) {
            int k = kc * 64 + kp + j;
            w0[j] = (short)f2b(fmaxf(fmaf(s, Wsi1[k], bsi1[k]), 0.f));
            w1[j] = (short)f2b(fmaxf(fmaf(s, Wsi1[k + 8], bsi1[k + 8]), 0.f));
        }
        *(short8*)&A[ar * 72 + kp] = w0;
        *(short8*)&A[ar * 72 + kp + 8] = w1;
#pragma unroll
        for (int j = 0; j < 4; ++j) {
            int ch = t + j * 256;
            int n2 = ch >> 3, ko = (ch & 7) * 8;
            *(short8*)&BT[n2 * 72 + ko] =
                *(const short8*)(Wsi2T + n2 * 256 + kc * 64 + ko);
        }
        __syncthreads();
#pragma unroll
        for (int ks = 0; ks < 2; ++ks) {
            short8 a[2], b[4];
#pragma unroll
            for (int m = 0; m < 2; ++m)
                a[m] = *(const short8*)&A[(wm * 32 + m * 16 + (lane & 15)) * 72 + ks * 32 + (lane >> 4) * 8];
#pragma unroll
            for (int n = 0; n < 4; ++n)
                b[n] = *(const short8*)&BT[(wn * 64 + n * 16 + (lane & 15)) * 72 + ks * 32 + (lane >> 4) * 8];
#pragma unroll
            for (int m = 0; m < 2; ++m)
#pragma unroll
                for (int n = 0; n < 4; ++n)
                    acc[m][n] = __builtin_amdgcn_mfma_f32_16x16x32_bf16(a[m], b[n], acc[m][n], 0, 0, 0);
        }
        __syncthreads();
    }
#pragma unroll
    for (int m = 0; m < 2; ++m)
#pragma unroll
    for (int n = 0; n < 4; ++n) {
        int col = wn * 64 + n * 16 + (lane & 15);
        float bias = bsi2[col];
#pragma unroll
        for (int r = 0; r < 4; ++r) {
            int row = rbase + wm * 32 + m * 16 + (lane >> 4) * 4 + r;
            spb[row * 128 + col] = f2b(acc[m][n][r] + bias);
        }
    }
}

// 1 block, 1024 threads: prefix-scan chunk counts -> chunk bases + pad table
__global__ __launch_bounds__(1024) void k_scan(
    const int* __restrict__ bcnt, int* __restrict__ chunkoff,
    int* __restrict__ pad) {
    __shared__ int sc[1024];
    __shared__ int tot[8];
    __shared__ int spo[8];
    const int t = threadIdx.x;
    for (int g = 0; g < 6; ++g) {
        int v = bcnt[t * 6 + g];
        sc[t] = v;
        __syncthreads();
        for (int s = 1; s < 1024; s <<= 1) {
            int u = (t >= s) ? sc[t - s] : 0;
            __syncthreads();
            sc[t] += u;
            __syncthreads();
        }
        if (t == 1023) tot[g] = sc[t];
        chunkoff[t * 6 + g] = sc[t] - v;   // exclusive, padoff added below
        __syncthreads();
    }
    if (t == 0) {
        int off = 0;
        for (int g = 0; g < 6; ++g) {
            spo[g] = off; pad[g] = off; pad[8 + g] = tot[g];
            off += ((tot[g] + 63) >> 6) << 6;
        }
        spo[6] = off; pad[6] = off;
    }
    __syncthreads();
    for (int g = 0; g < 6; ++g) chunkoff[t * 6 + g] += spo[g];
}

// deterministic scatter, no atomics: wave w handles 64-row chunk b*4+w
__global__ __launch_bounds__(256) void k_scatter(
    const int* __restrict__ cmd, const int* __restrict__ chunkoff,
    int* __restrict__ perm) {
    const int lane = threadIdx.x & 63, w = threadIdx.x >> 6;
    const int chunk = blockIdx.x * 4 + w;
    const int idx = chunk * 64 + lane;
    const int c = cmd[idx] - 1;
#pragma unroll
    for (int g = 0; g < 6; ++g) {
        unsigned long long m = __ballot(c == g);
        if (c == g) {
            int pos = chunkoff[chunk * 6 + g] + (int)__popcll(m & ((1ull << lane) - 1ull));
            perm[pos] = idx;
        }
    }
}

// -------- fused 3-layer head, counted-vmcnt L1 pipeline, overlaid LDS -------
__global__ __launch_bounds__(256, 3) void k_head(
    const float* __restrict__ emb, const bhalf* __restrict__ spb,
    const bhalf* __restrict__ Wso1T, const float* __restrict__ bso1,
    const bhalf* __restrict__ Wso2T, const float* __restrict__ bso2,
    const float* __restrict__ Wso3, const float* __restrict__ bso3,
    const bhalf* __restrict__ Wb1T, const float* __restrict__ bb1,
    const bhalf* __restrict__ Wb2T, const float* __restrict__ bb2,
    const float* __restrict__ Wb3, const float* __restrict__ bb3,
    const int* __restrict__ pad, const int* __restrict__ perm,
    float* __restrict__ out) {
    // [0,32768): L1 SB dbuf (2x16K)  -> after L1: Y (32K)
    // [32768,49152): L1 SA dbuf (2x8K f32) -> in L2: single B buffer (16K)
    __shared__ __align__(16) char L[49152];
    char* const SB0 = L;
    char* const SAr = L + 32768;
    char* const Yb  = L;
    const int t = threadIdx.x, lane = t & 63, wid = t >> 6;
    const bool isB = blockIdx.x < NBRB;
    int tstart, DOUT, gcnt, gbase;
    const bhalf *W1T, *W2T; const float *b1, *b2, *W3, *b3;
    if (isB) {
        tstart = blockIdx.x * 64;
        if (tstart >= pad[6]) return;
        int g = 0;
        while (pad[g + 1] <= tstart) ++g;
        gbase = pad[g]; gcnt = pad[8 + g];
        W1T = Wb1T + (size_t)g * (256 * 640); b1 = bb1 + g * 256;
        W2T = Wb2T + (size_t)g * (256 * 256); b2 = bb2 + g * 256;
        W3  = Wb3  + (size_t)g * (256 * 3);   b3 = bb3 + g * 3;
        DOUT = 3;
    } else {
        tstart = (blockIdx.x - NBRB) * 64;
        gbase = 0; gcnt = NB;
        W1T = Wso1T; b1 = bso1; W2T = Wso2T; b2 = bso2; W3 = Wso3; b3 = bso3;
        DOUT = 1;
    }

    // staging source maps
    const int rowA0 = t >> 3, rowA1 = rowA0 + 32, rowS = t >> 2;
    int ra0, ra1, raS;
    if (isB) {
        int p0 = tstart + rowA0, p1 = tstart + rowA1, pS = tstart + rowS;
        ra0 = ((p0 - gbase) < gcnt) ? perm[p0] : 0;
        ra1 = ((p1 - gbase) < gcnt) ? perm[p1] : 0;
        raS = ((pS - gbase) < gcnt) ? perm[pS] : 0;
    } else {
        ra0 = tstart + rowA0; ra1 = tstart + rowA1; raS = tstart + rowS;
    }
    const int lcA0 = ((t & 7) * 16) ^ ((rowA0 & 7) << 4);
    const int lcA1 = ((t & 7) * 16) ^ ((rowA1 & 7) << 4);
    const int lcS  = ((t & 3) * 16) ^ (((rowS >> 1) & 3) << 4);
    const char* embp0 = (const char*)(emb + (size_t)ra0 * 512);
    const char* embp1 = (const char*)(emb + (size_t)ra1 * 512);
    const char* spbp  = (const char*)(spb + (size_t)raS * 128);
    const int dstA = t * 16;
    const int rB = t >> 2, cB = (t & 3) * 16;

#define ST_A(KN, BUF) do { int kn_ = (KN); char* d_ = SAr + (BUF) * 8192 + dstA; \
        if (kn_ < 16) {                                                           \
            gll16(embp0 + kn_ * 128 + lcA0, d_);                                  \
            gll16(embp1 + kn_ * 128 + lcA1, d_ + 4096);                           \
        } else {                                                                  \
            gll16(spbp + (kn_ - 16) * 64 + lcS, d_);                              \
            gll16(spbp + (kn_ - 16) * 64 + lcS, d_ + 4096);                       \
        } } while (0)
#define ST_B1(KN, BUF) do {                                                       \
        _Pragma("unroll")                                                         \
        for (int j_ = 0; j_ < 4; ++j_) {                                          \
            int row_ = rB + j_ * 64;                                              \
            int p_ = row_ * 64 + cB;                                              \
            int lc_ = cB ^ (((row_ >> 1) & 3) << 4);                              \
            gll16((const char*)W1T + (size_t)row_ * 1280 + (KN) * 64 + lc_,       \
                  SB0 + (BUF) * 16384 + p_);                                      \
        } } while (0)
#define ST_B2(KB) do {                                                            \
        _Pragma("unroll")                                                         \
        for (int j_ = 0; j_ < 4; ++j_) {                                          \
            int row_ = rB + j_ * 64;                                              \
            int p_ = row_ * 64 + cB;                                              \
            int lc_ = cB ^ (((row_ >> 1) & 3) << 4);                              \
            gll16((const char*)W2T + (size_t)row_ * 512 + (KB) + lc_,             \
                  SAr + p_);                                                      \
        } } while (0)

    const int arow = lane & 15, koff = (lane >> 4) * 16;
    float bi1[4], bi2[4];
#pragma unroll
    for (int n = 0; n < 4; ++n) {
        bi1[n] = b1[wid * 64 + n * 16 + arow];
        bi2[n] = b2[wid * 64 + n * 16 + arow];
    }

    f32x4 acc[4][4];
#pragma unroll
    for (int m = 0; m < 4; ++m)
#pragma unroll
        for (int n = 0; n < 4; ++n)
#pragma unroll
            for (int r = 0; r < 4; ++r) acc[m][n][r] = 0.f;

    // ---------------- layer 1: K=640, 20 sections, counted pipeline ---------
    ST_A(0, 0); ST_B1(0, 0);                 // 6 outstanding
    for (int kc = 0; kc < 20; ++kc) {
        const int buf = kc & 1;
        if (kc < 19) { ST_A(kc + 1, buf ^ 1); ST_B1(kc + 1, buf ^ 1); wvm6(); }
        else         { wvm0(); }
        __builtin_amdgcn_s_barrier();
        const char* SAc = SAr + buf * 8192;
        const char* SBc = SB0 + buf * 16384;
        short8 a[4], b[4];
#pragma unroll
        for (int n = 0; n < 4; ++n)
            b[n] = *(const short8*)(SBc + sadr(wid * 64 + n * 16 + arow, koff));
        if (kc < 16) {
#pragma unroll
            for (int m = 0; m < 4; ++m) {
                int row = m * 16 + arow;
                int sw = (row & 7) << 4;
                int c0 = (lane >> 4) * 32;
                float4 f0 = *(const float4*)(SAc + row * 128 + (c0 ^ sw));
                float4 f1 = *(const float4*)(SAc + row * 128 + ((c0 + 16) ^ sw));
                a[m][0] = (short)f2b(f0.x); a[m][1] = (short)f2b(f0.y);
                a[m][2] = (short)f2b(f0.z); a[m][3] = (short)f2b(f0.w);
                a[m][4] = (short)f2b(f1.x); a[m][5] = (short)f2b(f1.y);
                a[m][6] = (short)f2b(f1.z); a[m][7] = (short)f2b(f1.w);
            }
        } else {
#pragma unroll
            for (int m = 0; m < 4; ++m)
                a[m] = *(const short8*)(SAc + sadr(m * 16 + arow, koff));
        }
#pragma unroll
        for (int m = 0; m < 4; ++m)
#pragma unroll
            for (int n = 0; n < 4; ++n)
                acc[m][n] = __builtin_amdgcn_mfma_f32_16x16x32_bf16(a[m], b[n], acc[m][n], 0, 0, 0);
        __builtin_amdgcn_s_barrier();
    }
    // epi 1: bias+relu -> Y (overlays SB region; all L1 SB reads done)
#pragma unroll
    for (int m = 0; m < 4; ++m)
#pragma unroll
    for (int n = 0; n < 4; ++n) {
        int col = wid * 64 + n * 16 + arow;
#pragma unroll
        for (int r = 0; r < 4; ++r) {
            int row = m * 16 + (lane >> 4) * 4 + r;
            *(bhalf*)(Yb + yadr(row, 2 * col)) = f2b(fmaxf(acc[m][n][r] + bi1[n], 0.f));
            acc[m][n][r] = 0.f;
        }
    }
    // stage L2 sec0 into SAr (L1 SA reads done); make Y + B visible
    ST_B2(0);
    wlgkm0();
    wvm0();
    __builtin_amdgcn_s_barrier();
    // ---------------- layer 2: K=256, 8 sections, single-buffered -----------
    for (int kc = 0; kc < 8; ++kc) {
        short8 a[4], b[4];
#pragma unroll
        for (int m = 0; m < 4; ++m)
            a[m] = *(const short8*)(Yb + yadr(m * 16 + arow, kc * 64 + koff));
#pragma unroll
        for (int n = 0; n < 4; ++n)
            b[n] = *(const short8*)(SAr + sadr(wid * 64 + n * 16 + arow, koff));
#pragma unroll
        for (int m = 0; m < 4; ++m)
#pragma unroll
            for (int n = 0; n < 4; ++n)
                acc[m][n] = __builtin_amdgcn_mfma_f32_16x16x32_bf16(a[m], b[n], acc[m][n], 0, 0, 0);
        __builtin_amdgcn_s_barrier();            // all reads of SAr done
        if (kc < 7) { ST_B2((kc + 1) * 64); wvm0(); }
        __builtin_amdgcn_s_barrier();            // next tile ready
    }
    // epi 2: bias+relu -> Y
#pragma unroll
    for (int m = 0; m < 4; ++m)
#pragma unroll
    for (int n = 0; n < 4; ++n) {
        int col = wid * 64 + n * 16 + arow;
#pragma unroll
        for (int r = 0; r < 4; ++r) {
            int row = m * 16 + (lane >> 4) * 4 + r;
            *(bhalf*)(Yb + yadr(row, 2 * col)) = f2b(fmaxf(acc[m][n][r] + bi2[n], 0.f));
        }
    }
    wlgkm0();
    __builtin_amdgcn_s_barrier();
    // ---------------- layer 3: MFMA, wave w owns rows w*16..w*16+15 ---------
    f32x4 z;
#pragma unroll
    for (int r = 0; r < 4; ++r) z[r] = 0.f;
    const int col3 = arow;
    for (int kc = 0; kc < 8; ++kc) {
        short8 a3 = *(const short8*)(Yb + yadr(wid * 16 + arow, kc * 64 + koff));
        short8 bw;
#pragma unroll
        for (int j = 0; j < 8; ++j) bw[j] = 0;
        if (col3 < DOUT) {
            int kb = kc * 32 + (lane >> 4) * 8;
#pragma unroll
            for (int j = 0; j < 8; ++j)
                bw[j] = (short)f2b(W3[(kb + j) * DOUT + col3]);
        }
        z = __builtin_amdgcn_mfma_f32_16x16x32_bf16(a3, bw, z, 0, 0, 0);
    }
    if (col3 < DOUT) {
        float bias = b3[col3];
#pragma unroll
        for (int rr = 0; rr < 4; ++rr) {
            int r = wid * 16 + (lane >> 4) * 4 + rr;
            int p2 = tstart + r;
            if ((p2 - gbase) < gcnt) {
                float v = z[rr] + bias;
                if (isB) {
                    int ro = perm[p2];
                    out[(size_t)ro * 3 + col3] = 1.f / (1.f + __expf(-v));
                } else {
                    out[(size_t)NB * 3 + p2] = v;
                }
            }
        }
    }
#undef ST_A
#undef ST_B1
#undef ST_B2
}

extern "C" void kernel_launch(void* const* d_in, const int* in_sizes, int n_in,
                              void* d_out, int out_size, void* d_ws, size_t ws_size,
                              hipStream_t stream) {
    (void)in_sizes; (void)n_in; (void)out_size; (void)ws_size;
    const float* emb   = (const float*)d_in[0];
    const float* speed = (const float*)d_in[1];
    const int*   cmd   = (const int*)d_in[2];
    const float* Wsi1  = (const float*)d_in[3];
    const float* bsi1  = (const float*)d_in[4];
    const float* Wsi2  = (const float*)d_in[5];
    const float* bsi2  = (const float*)d_in[6];
    const float* Wso1  = (const float*)d_in[7];
    const float* bso1  = (const float*)d_in[8];
    const float* Wso2  = (const float*)d_in[9];
    const float* bso2  = (const float*)d_in[10];
    const float* Wso3  = (const float*)d_in[11];
    const float* bso3  = (const float*)d_in[12];
    const float* Wb1   = (const float*)d_in[13];
    const float* bb1   = (const float*)d_in[14];
    const float* Wb2   = (const float*)d_in[15];
    const float* bb2   = (const float*)d_in[16];
    const float* Wb3   = (const float*)d_in[17];
    const float* bb3   = (const float*)d_in[18];
    float* out = (float*)d_out;

    char* ws = (char*)d_ws;
    bhalf* spb      = (bhalf*)(ws);
    int*   perm     = (int*)(ws + 16777216);
    int*   bcnt     = (int*)(ws + 17040896);
    int*   chunkoff = (int*)(ws + 17065472);
    int*   pad      = (int*)(ws + 17090048);
    bhalf* Wsi2T    = (bhalf*)(ws + 17090304);
    bhalf* Wso1T    = (bhalf*)(ws + 17155840);
    bhalf* Wso2T    = (bhalf*)(ws + 17483520);
    bhalf* Wb1T     = (bhalf*)(ws + 17614592);
    bhalf* Wb2T     = (bhalf*)(ws + 19580672);

    k_wprep<<<400, 256, 0, stream>>>(Wsi2, Wso1, Wso2, Wb1, Wb2,
                                     Wsi2T, Wso1T, Wso2T, Wb1T, Wb2T);
    k_prep<<<NB / 64, 256, 0, stream>>>(speed, Wsi1, bsi1, Wsi2T, bsi2, cmd,
                                        spb, bcnt);
    k_scan<<<1, 1024, 0, stream>>>(bcnt, chunkoff, pad);
    k_scatter<<<NB / 256, 256, 0, stream>>>(cmd, chunkoff, perm);
    k_head<<<NBRB + NB / 64, 256, 0, stream>>>(emb, spb,
                                               Wso1T, bso1, Wso2T, bso2, Wso3, bso3,
                                               Wb1T, bb1, Wb2T, bb2, Wb3, bb3,
                                               pad, perm, out);
}